// Round 1
// baseline (2151.905 us; speedup 1.0000x reference)
//
#include <hip/hip_runtime.h>
#include <hip/hip_bf16.h>
#include <stdint.h>

#define NN 8192
#define EE 32768
#define BB 256
#define DD 64
#define FIN 11
#define EIN 5
#define HH 128

__device__ __forceinline__ float sigmoidf_(float x) { return 1.0f / (1.0f + expf(-x)); }
__device__ __forceinline__ float bflo(unsigned u) { return __uint_as_float(u << 16); }
__device__ __forceinline__ float bfhi(unsigned u) { return __uint_as_float(u & 0xffff0000u); }

// ---------------- permute nn2_w rows: B'[f*64+d] = nn2_w[d*64+f] ----------------
__global__ __launch_bounds__(256) void k_permute(const float* __restrict__ nn2_w,
                                                 const float* __restrict__ nn2_b,
                                                 float* __restrict__ nn2P,
                                                 float* __restrict__ bP) {
    int idx = blockIdx.x * 256 + threadIdx.x;      // over 4096*128
    int j = idx >> 7, k = idx & 127;
    int d = j >> 6, f = j & 63;
    int jr = f * 64 + d;
    nn2P[(size_t)jr * 128 + k] = nn2_w[idx];
    if (k == 0) bP[jr] = nn2_b[j];
}

// ---------------- lin0: out = relu(x @ lin0_w.T + b) ----------------
__global__ __launch_bounds__(256) void k_lin0(const float* __restrict__ x,
                                              const float* __restrict__ w,
                                              const float* __restrict__ b,
                                              float* __restrict__ out) {
    int idx = blockIdx.x * 256 + threadIdx.x;      // over N*64
    int n = idx >> 6, d = idx & 63;
    float a = b[d];
#pragma unroll
    for (int k = 0; k < FIN; k++) a += x[n * FIN + k] * w[d * FIN + k];
    out[idx] = fmaxf(a, 0.0f);
}

// ---------------- h1 = relu(edge_attr @ nn1_w.T + b) ----------------
__global__ __launch_bounds__(256) void k_h1(const float* __restrict__ ea,
                                            const float* __restrict__ w,
                                            const float* __restrict__ b,
                                            float* __restrict__ h1) {
    int idx = blockIdx.x * 256 + threadIdx.x;      // over E*128
    int e = idx >> 7, k = idx & 127;
    float a = b[k];
#pragma unroll
    for (int j = 0; j < EIN; j++) a += ea[e * EIN + j] * w[k * EIN + j];
    h1[idx] = fmaxf(a, 0.0f);
}

// ---------------- degree ----------------
__global__ __launch_bounds__(256) void k_count(const int* __restrict__ ei, int* __restrict__ deg) {
    int e = blockIdx.x * 256 + threadIdx.x;
    if (e < EE) atomicAdd(&deg[ei[EE + e]], 1);
}
__global__ __launch_bounds__(256) void k_inv(const int* __restrict__ deg, float* __restrict__ invd) {
    int n = blockIdx.x * 256 + threadIdx.x;
    if (n < NN) { int d = deg[n]; invd[n] = d > 0 ? 1.0f / (float)d : 0.0f; }
}

// ---------------- generic tiled GEMM: C[row,col] = A[row,:K] . Bm[col,:K] (+bias) ----------------
// M, N multiples of 64. A row-major [M,K], Bm row-major [N,K]. grid = (N/64, M/64).
template <int OUT_BF16, int K>
__global__ __launch_bounds__(256) void k_gemm(const float* __restrict__ A,
                                              const float* __restrict__ Bm,
                                              const float* __restrict__ bias,
                                              void* __restrict__ C, int ldc) {
    __shared__ float sA[64 * 132];
    __shared__ float sB[64 * 132];
    const int tid = threadIdx.x;
    const int bx = blockIdx.x, by = blockIdx.y;
    const float* Ab = A + (size_t)by * 64 * K;
    const float* Bb = Bm + (size_t)bx * 64 * K;
    const int k4 = K >> 2;
    for (int fi = tid; fi < 64 * k4; fi += 256) {
        int r = fi / k4, c = fi % k4;
        float4 av = reinterpret_cast<const float4*>(Ab + (size_t)r * K)[c];
        *reinterpret_cast<float4*>(&sA[r * 132 + c * 4]) = av;
        float4 bv = reinterpret_cast<const float4*>(Bb + (size_t)r * K)[c];
        *reinterpret_cast<float4*>(&sB[r * 132 + c * 4]) = bv;
    }
    __syncthreads();
    const int tx = tid & 15, ty = tid >> 4;
    float acc[4][4];
#pragma unroll
    for (int i = 0; i < 4; i++)
#pragma unroll
        for (int j = 0; j < 4; j++) acc[i][j] = 0.0f;
    for (int k = 0; k < K; k += 4) {
        float4 av[4], bv[4];
#pragma unroll
        for (int i = 0; i < 4; i++) av[i] = *reinterpret_cast<const float4*>(&sA[(ty + 16 * i) * 132 + k]);
#pragma unroll
        for (int j = 0; j < 4; j++) bv[j] = *reinterpret_cast<const float4*>(&sB[(tx + 16 * j) * 132 + k]);
#pragma unroll
        for (int i = 0; i < 4; i++)
#pragma unroll
            for (int j = 0; j < 4; j++) {
                acc[i][j] += av[i].x * bv[j].x;
                acc[i][j] += av[i].y * bv[j].y;
                acc[i][j] += av[i].z * bv[j].z;
                acc[i][j] += av[i].w * bv[j].w;
            }
    }
#pragma unroll
    for (int i = 0; i < 4; i++) {
        size_t row = (size_t)by * 64 + ty + 16 * i;
#pragma unroll
        for (int j = 0; j < 4; j++) {
            int col = bx * 64 + tx + 16 * j;
            float v = acc[i][j];
            if (bias) v += bias[col];
            if (OUT_BF16)
                ((__hip_bfloat16*)C)[row * ldc + col] = __float2bfloat16(v);
            else
                ((float*)C)[row * ldc + col] = v;
        }
    }
}

// ---------------- message + scatter: agg[dst,f] += sum_d out[src,d]*W_e[e,d,f] ----------------
// Wt layout: [ec][f*64+d] bf16 (transposed via permuted B rows). 4 edges/block, 64 lanes/edge.
__global__ __launch_bounds__(256) void k_msg(const __hip_bfloat16* __restrict__ Wt,
                                             const float* __restrict__ out,
                                             const int* __restrict__ ei,
                                             int e0,
                                             float* __restrict__ agg) {
    const int tid = threadIdx.x;
    const int sub = tid >> 6, lane = tid & 63;
    const int ec = blockIdx.x * 4 + sub;           // chunk-local edge
    const int e = e0 + ec;
    const int src = ei[e], dst = ei[EE + e];
    __shared__ float so[4][64];
    so[sub][lane] = out[(size_t)src * 64 + lane];
    __syncthreads();
    const float* o = so[sub];
    const uint4* wp = reinterpret_cast<const uint4*>(Wt) + ((size_t)ec * 512 + lane * 8);
    float acc = 0.0f;
#pragma unroll
    for (int c = 0; c < 8; c++) {
        uint4 u = wp[c];
        const float* o8 = o + c * 8;
        acc += o8[0] * bflo(u.x) + o8[1] * bfhi(u.x);
        acc += o8[2] * bflo(u.y) + o8[3] * bfhi(u.y);
        acc += o8[4] * bflo(u.z) + o8[5] * bfhi(u.z);
        acc += o8[6] * bflo(u.w) + o8[7] * bfhi(u.w);
    }
    atomicAdd(&agg[(size_t)dst * 64 + lane], acc);
}

// ---------------- m = relu(agg*inv_deg + rootC + conv_b) ----------------
__global__ __launch_bounds__(256) void k_m(const float* __restrict__ agg,
                                           const float* __restrict__ invd,
                                           const float* __restrict__ rootC,
                                           const float* __restrict__ cb,
                                           float* __restrict__ m) {
    int idx = blockIdx.x * 256 + threadIdx.x;
    int n = idx >> 6, d = idx & 63;
    m[idx] = fmaxf(agg[idx] * invd[n] + rootC[idx] + cb[d], 0.0f);
}

// ---------------- GRU elementwise: out = (1-z)*n + z*h ----------------
__global__ __launch_bounds__(256) void k_gru(const float* __restrict__ gx,
                                             const float* __restrict__ gh,
                                             float* __restrict__ out) {
    int idx = blockIdx.x * 256 + threadIdx.x;
    int n = idx >> 6, d = idx & 63;
    const float* gxr = gx + (size_t)n * 192;
    const float* ghr = gh + (size_t)n * 192;
    float r = sigmoidf_(gxr[d] + ghr[d]);
    float z = sigmoidf_(gxr[64 + d] + ghr[64 + d]);
    float nn_ = tanhf(gxr[128 + d] + r * ghr[128 + d]);
    float hp = out[idx];
    out[idx] = (1.0f - z) * nn_ + z * hp;
}

// ---------------- batch counting + scan ----------------
__global__ __launch_bounds__(256) void k_cntbatch(const int* __restrict__ batch, int* __restrict__ cnt) {
    int n = blockIdx.x * 256 + threadIdx.x;
    if (n < NN) atomicAdd(&cnt[batch[n]], 1);
}
__global__ __launch_bounds__(256) void k_scan(const int* __restrict__ cnt, int* __restrict__ offs) {
    __shared__ int s[256];
    int t = threadIdx.x;
    s[t] = cnt[t];
    __syncthreads();
    for (int off = 1; off < 256; off <<= 1) {
        int v = (t >= off) ? s[t - off] : 0;
        __syncthreads();
        s[t] += v;
        __syncthreads();
    }
    offs[t + 1] = s[t];
    if (t == 0) offs[0] = 0;
}

// ---------------- Set2Set LSTM step: gates + cell update ----------------
__global__ __launch_bounds__(256) void k_s2s(const float* __restrict__ qstar,
                                             float* __restrict__ qh, float* __restrict__ qc,
                                             const float* __restrict__ wih, const float* __restrict__ whh,
                                             const float* __restrict__ bih, const float* __restrict__ bhh) {
    int b = blockIdx.x, j = threadIdx.x;           // 256 threads = 256 gate outputs
    float g = bih[j] + bhh[j];
    const float* qs = qstar + (size_t)b * 128;
    const float* qhr = qh + (size_t)b * 64;
    for (int k = 0; k < 128; k++) g += qs[k] * wih[j * 128 + k];
    for (int k = 0; k < 64; k++) g += qhr[k] * whh[j * 64 + k];
    __shared__ float sg[256];
    sg[j] = g;
    __syncthreads();
    if (j < 64) {
        float gi = sg[j], gf = sg[64 + j], gg = sg[128 + j], go = sg[192 + j];
        float c = sigmoidf_(gf) * qc[b * 64 + j] + sigmoidf_(gi) * tanhf(gg);
        float h = sigmoidf_(go) * tanhf(c);
        qc[b * 64 + j] = c;
        qh[b * 64 + j] = h;
    }
}

// ---------------- e[n] = dot(out[n,:], qh[batch[n],:]) ----------------
__global__ __launch_bounds__(256) void k_e(const float* __restrict__ out,
                                           const float* __restrict__ qh,
                                           const int* __restrict__ batch,
                                           float* __restrict__ earr) {
    int n = blockIdx.x * 4 + (threadIdx.x >> 6);
    int lane = threadIdx.x & 63;
    float p = out[(size_t)n * 64 + lane] * qh[(size_t)batch[n] * 64 + lane];
#pragma unroll
    for (int o = 32; o > 0; o >>= 1) p += __shfl_xor(p, o, 64);
    if (lane == 0) earr[n] = p;
}

// ---------------- per-graph softmax + weighted sum -> q_star ----------------
__global__ __launch_bounds__(64) void k_seg(const int* __restrict__ offs,
                                            const float* __restrict__ earr,
                                            const float* __restrict__ out,
                                            const float* __restrict__ qh,
                                            float* __restrict__ qstar) {
    int b = blockIdx.x, lane = threadIdx.x;        // 64 threads
    int s0 = offs[b], s1 = offs[b + 1];
    float mx = -INFINITY;
    for (int i = s0 + lane; i < s1; i += 64) mx = fmaxf(mx, earr[i]);
#pragma unroll
    for (int o = 32; o > 0; o >>= 1) mx = fmaxf(mx, __shfl_xor(mx, o, 64));
    if (!isfinite(mx)) mx = 0.0f;
    float sm = 0.0f;
    for (int i = s0 + lane; i < s1; i += 64) sm += expf(earr[i] - mx);
#pragma unroll
    for (int o = 32; o > 0; o >>= 1) sm += __shfl_xor(sm, o, 64);
    float r = 0.0f;
    for (int i = s0; i < s1; i++) r += expf(earr[i] - mx) * out[(size_t)i * 64 + lane];
    r /= fmaxf(sm, 1e-12f);
    qstar[(size_t)b * 128 + 64 + lane] = r;
    qstar[(size_t)b * 128 + lane] = qh[(size_t)b * 64 + lane];
}

// ---------------- head: y = relu(q_star@lin1.T+b1)@lin2.T + b2 ----------------
__global__ __launch_bounds__(64) void k_final(const float* __restrict__ qstar,
                                              const float* __restrict__ w1, const float* __restrict__ b1,
                                              const float* __restrict__ w2, const float* __restrict__ b2,
                                              float* __restrict__ y) {
    int b = blockIdx.x, j = threadIdx.x;           // 64 threads
    float h = b1[j];
    const float* qs = qstar + (size_t)b * 128;
    for (int k = 0; k < 128; k++) h += qs[k] * w1[j * 128 + k];
    h = fmaxf(h, 0.0f);
    float p = h * w2[j];
#pragma unroll
    for (int o = 32; o > 0; o >>= 1) p += __shfl_xor(p, o, 64);
    if (j == 0) y[b] = p + b2[0];
}

extern "C" void kernel_launch(void* const* d_in, const int* in_sizes, int n_in,
                              void* d_out, int out_size, void* d_ws, size_t ws_size,
                              hipStream_t stream) {
    const float* x = (const float*)d_in[0];
    const float* edge_attr = (const float*)d_in[1];
    const float* lin0_w = (const float*)d_in[2];
    const float* lin0_b = (const float*)d_in[3];
    const float* nn1_w = (const float*)d_in[4];
    const float* nn1_b = (const float*)d_in[5];
    const float* nn2_w = (const float*)d_in[6];
    const float* nn2_b = (const float*)d_in[7];
    const float* root_w = (const float*)d_in[8];
    const float* conv_b = (const float*)d_in[9];
    const float* gru_w_ih = (const float*)d_in[10];
    const float* gru_w_hh = (const float*)d_in[11];
    const float* gru_b_ih = (const float*)d_in[12];
    const float* gru_b_hh = (const float*)d_in[13];
    const float* s2s_w_ih = (const float*)d_in[14];
    const float* s2s_w_hh = (const float*)d_in[15];
    const float* s2s_b_ih = (const float*)d_in[16];
    const float* s2s_b_hh = (const float*)d_in[17];
    const float* lin1_w = (const float*)d_in[18];
    const float* lin1_b = (const float*)d_in[19];
    const float* lin2_w = (const float*)d_in[20];
    const float* lin2_b = (const float*)d_in[21];
    const int* ei = (const int*)d_in[22];
    const int* batch = (const int*)d_in[23];
    float* outp = (float*)d_out;

    // workspace carve (256B aligned)
    char* w = (char*)d_ws;
    auto carve = [&](size_t bytes) { char* p = w; w += (bytes + 255) & ~(size_t)255; return p; };
    float* nn2P = (float*)carve((size_t)4096 * 128 * 4);
    float* bP = (float*)carve(4096 * 4);
    float* outN = (float*)carve((size_t)NN * 64 * 4);
    float* h1 = (float*)carve((size_t)EE * 128 * 4);
    int* deg = (int*)carve(NN * 4);
    float* invd = (float*)carve(NN * 4);
    float* agg = (float*)carve((size_t)NN * 64 * 4);
    float* rootC = (float*)carve((size_t)NN * 64 * 4);
    float* mbuf = (float*)carve((size_t)NN * 64 * 4);
    float* gx = (float*)carve((size_t)NN * 192 * 4);
    float* gh = (float*)carve((size_t)NN * 192 * 4);
    float* earr = (float*)carve(NN * 4);
    int* cnt = (int*)carve(256 * 4);
    int* offs = (int*)carve(257 * 4);
    float* qh = (float*)carve((size_t)BB * 64 * 4);
    float* qc = (float*)carve((size_t)BB * 64 * 4);
    float* qstar = (float*)carve((size_t)BB * 128 * 4);
    size_t used = (size_t)(w - (char*)d_ws);
    size_t remain = ws_size > used ? ws_size - used : 0;
    size_t cap = (remain / ((size_t)4096 * 2)) & ~(size_t)63;
    int chunkE = (int)(cap > (size_t)EE ? (size_t)EE : cap);
    if (chunkE < 64) chunkE = 64;
    bool persist = (chunkE >= EE);
    if (persist) chunkE = EE;
    __hip_bfloat16* Wt = (__hip_bfloat16*)w;

    hipMemsetAsync(deg, 0, NN * 4, stream);
    hipMemsetAsync(cnt, 0, 256 * 4, stream);
    hipMemsetAsync(qh, 0, BB * 64 * 4, stream);
    hipMemsetAsync(qc, 0, BB * 64 * 4, stream);
    hipMemsetAsync(qstar, 0, BB * 128 * 4, stream);

    k_permute<<<2048, 256, 0, stream>>>(nn2_w, nn2_b, nn2P, bP);
    k_lin0<<<NN * 64 / 256, 256, 0, stream>>>(x, lin0_w, lin0_b, outN);
    k_h1<<<EE * 128 / 256, 256, 0, stream>>>(edge_attr, nn1_w, nn1_b, h1);
    k_count<<<EE / 256, 256, 0, stream>>>(ei, deg);
    k_inv<<<NN / 256, 256, 0, stream>>>(deg, invd);
    k_cntbatch<<<NN / 256, 256, 0, stream>>>(batch, cnt);
    k_scan<<<1, 256, 0, stream>>>(cnt, offs);

    if (persist)
        k_gemm<1, 128><<<dim3(64, EE / 64), 256, 0, stream>>>(h1, nn2P, bP, Wt, 4096);

    for (int it = 0; it < 3; it++) {
        hipMemsetAsync(agg, 0, (size_t)NN * 64 * 4, stream);
        for (int e0 = 0; e0 < EE; e0 += chunkE) {
            int ce = (EE - e0) < chunkE ? (EE - e0) : chunkE;
            if (!persist)
                k_gemm<1, 128><<<dim3(64, ce / 64), 256, 0, stream>>>(h1 + (size_t)e0 * 128, nn2P, bP, Wt, 4096);
            k_msg<<<ce / 4, 256, 0, stream>>>(Wt, outN, ei, e0, agg);
        }
        k_gemm<0, 64><<<dim3(1, NN / 64), 256, 0, stream>>>(outN, root_w, nullptr, rootC, 64);
        k_m<<<NN * 64 / 256, 256, 0, stream>>>(agg, invd, rootC, conv_b, mbuf);
        k_gemm<0, 64><<<dim3(3, NN / 64), 256, 0, stream>>>(mbuf, gru_w_ih, gru_b_ih, gx, 192);
        k_gemm<0, 64><<<dim3(3, NN / 64), 256, 0, stream>>>(outN, gru_w_hh, gru_b_hh, gh, 192);
        k_gru<<<NN * 64 / 256, 256, 0, stream>>>(gx, gh, outN);
    }

    for (int st = 0; st < 3; st++) {
        k_s2s<<<BB, 256, 0, stream>>>(qstar, qh, qc, s2s_w_ih, s2s_w_hh, s2s_b_ih, s2s_b_hh);
        k_e<<<NN / 4, 256, 0, stream>>>(outN, qh, batch, earr);
        k_seg<<<BB, 64, 0, stream>>>(offs, earr, outN, qh, qstar);
    }
    k_final<<<BB, 64, 0, stream>>>(qstar, lin1_w, lin1_b, lin2_w, lin2_b, outp);
}

// Round 2
// 808.507 us; speedup vs baseline: 2.6616x; 2.6616x over previous
//
#include <hip/hip_runtime.h>
#include <hip/hip_bf16.h>
#include <stdint.h>

#define NN 8192
#define EE 32768
#define BB 256
#define DD 64
#define FIN 11
#define EIN 5
#define HH 128

typedef __attribute__((ext_vector_type(4))) float f32x4;
typedef __attribute__((ext_vector_type(8))) short bf16x8;

__device__ __forceinline__ float sigmoidf_(float x) { return 1.0f / (1.0f + expf(-x)); }
__device__ __forceinline__ float bflo(unsigned u) { return __uint_as_float(u << 16); }
__device__ __forceinline__ float bfhi(unsigned u) { return __uint_as_float(u & 0xffff0000u); }

__device__ __forceinline__ void gload16(const void* g, void* l) {
    __builtin_amdgcn_global_load_lds(
        (const __attribute__((address_space(1))) unsigned int*)g,
        (__attribute__((address_space(3))) unsigned int*)l, 16, 0, 0);
}

// ---------------- permute nn2_w rows -> bf16: B'[f*64+d][k] = nn2_w[(d*64+f)][k] ----------------
__global__ __launch_bounds__(256) void k_permute(const float* __restrict__ nn2_w,
                                                 const float* __restrict__ nn2_b,
                                                 __hip_bfloat16* __restrict__ nn2P,
                                                 float* __restrict__ bP) {
    int idx = blockIdx.x * 256 + threadIdx.x;      // over 4096*128
    int j = idx >> 7, k = idx & 127;
    int d = j >> 6, f = j & 63;
    int jr = f * 64 + d;
    nn2P[(size_t)jr * 128 + k] = __float2bfloat16(nn2_w[idx]);
    if (k == 0) bP[jr] = nn2_b[j];
}

// ---------------- lin0: out = relu(x @ lin0_w.T + b) ----------------
__global__ __launch_bounds__(256) void k_lin0(const float* __restrict__ x,
                                              const float* __restrict__ w,
                                              const float* __restrict__ b,
                                              float* __restrict__ out) {
    int idx = blockIdx.x * 256 + threadIdx.x;      // over N*64
    int n = idx >> 6, d = idx & 63;
    float a = b[d];
#pragma unroll
    for (int k = 0; k < FIN; k++) a += x[n * FIN + k] * w[d * FIN + k];
    out[idx] = fmaxf(a, 0.0f);
}

// ---------------- h1 = relu(edge_attr @ nn1_w.T + b) -> bf16 ----------------
__global__ __launch_bounds__(256) void k_h1(const float* __restrict__ ea,
                                            const float* __restrict__ w,
                                            const float* __restrict__ b,
                                            __hip_bfloat16* __restrict__ h1) {
    int idx = blockIdx.x * 256 + threadIdx.x;      // over E*128
    int e = idx >> 7, k = idx & 127;
    float a = b[k];
#pragma unroll
    for (int j = 0; j < EIN; j++) a += ea[e * EIN + j] * w[k * EIN + j];
    h1[idx] = __float2bfloat16(fmaxf(a, 0.0f));
}

// ---------------- degree ----------------
__global__ __launch_bounds__(256) void k_count(const int* __restrict__ ei, int* __restrict__ deg) {
    int e = blockIdx.x * 256 + threadIdx.x;
    if (e < EE) atomicAdd(&deg[ei[EE + e]], 1);
}
__global__ __launch_bounds__(256) void k_inv(const int* __restrict__ deg, float* __restrict__ invd) {
    int n = blockIdx.x * 256 + threadIdx.x;
    if (n < NN) { int d = deg[n]; invd[n] = d > 0 ? 1.0f / (float)d : 0.0f; }
}

// ---------------- MFMA bf16 GEMM: C[row,col]=A[row,:128].B[col,:128]+bias[col], bf16 out ----------------
// A [M,128] bf16, B [4096,128] bf16 (B^T layout). grid=(32, M/128), 256 thr (4 waves).
// LDS linear, inverse-swizzled global source, XOR-swizzled ds_read (guide §5 rule 21 / T2).
__global__ __launch_bounds__(256) void k_we(const __hip_bfloat16* __restrict__ A,
                                            const __hip_bfloat16* __restrict__ Bm,
                                            const float* __restrict__ bias,
                                            __hip_bfloat16* __restrict__ C) {
    __shared__ ushort sA[128 * 128];
    __shared__ ushort sB[128 * 128];
    const int t = threadIdx.x;
    const int w = t >> 6, l = t & 63;
    const int bx = blockIdx.x, by = blockIdx.y;
    // stage: 2048 16B-units per tile; unit u -> row=u>>4, c=u&15, src col-unit = c^(row&7)
#pragma unroll
    for (int i = 0; i < 8; i++) {
        int u = w * 512 + i * 64 + l;
        int r = u >> 4, c = u & 15;
        int cs = c ^ (r & 7);
        gload16(A + ((size_t)(by * 128 + r) * 128 + cs * 8), &sA[(size_t)(w * 512 + i * 64) * 8]);
    }
#pragma unroll
    for (int i = 0; i < 8; i++) {
        int u = w * 512 + i * 64 + l;
        int r = u >> 4, c = u & 15;
        int cs = c ^ (r & 7);
        gload16(Bm + ((size_t)(bx * 128 + r) * 128 + cs * 8), &sB[(size_t)(w * 512 + i * 64) * 8]);
    }
    __syncthreads();

    const int wrow = w >> 1, wcol = w & 1;         // wave's 64x64 quadrant
    f32x4 acc[4][4];
#pragma unroll
    for (int i = 0; i < 4; i++)
#pragma unroll
        for (int j = 0; j < 4; j++) acc[i][j] = (f32x4)0.0f;

#pragma unroll
    for (int kk = 0; kk < 4; kk++) {
        const int u16 = kk * 4 + (l >> 4);
        bf16x8 af[4], bfr[4];
#pragma unroll
        for (int mi = 0; mi < 4; mi++) {
            int r = wrow * 64 + mi * 16 + (l & 15);
            af[mi] = *(const bf16x8*)&sA[(size_t)(r * 16 + (u16 ^ (r & 7))) * 8];
        }
#pragma unroll
        for (int ni = 0; ni < 4; ni++) {
            int r = wcol * 64 + ni * 16 + (l & 15);
            bfr[ni] = *(const bf16x8*)&sB[(size_t)(r * 16 + (u16 ^ (r & 7))) * 8];
        }
#pragma unroll
        for (int mi = 0; mi < 4; mi++)
#pragma unroll
            for (int ni = 0; ni < 4; ni++)
                acc[mi][ni] = __builtin_amdgcn_mfma_f32_16x16x32_bf16(af[mi], bfr[ni], acc[mi][ni], 0, 0, 0);
    }

    // epilogue: C/D map col=lane&15, row=(lane>>4)*4+reg
#pragma unroll
    for (int mi = 0; mi < 4; mi++) {
#pragma unroll
        for (int ni = 0; ni < 4; ni++) {
            int gcol = bx * 128 + wcol * 64 + ni * 16 + (l & 15);
            float bv = bias[gcol];
#pragma unroll
            for (int j = 0; j < 4; j++) {
                int grow = by * 128 + wrow * 64 + mi * 16 + (l >> 4) * 4 + j;
                C[(size_t)grow * 4096 + gcol] = __float2bfloat16(acc[mi][ni][j] + bv);
            }
        }
    }
}

// ---------------- f32 tiled GEMM (small): C[row,col] = A[row,:64].Bm[col,:64] (+bias) ----------------
template <int K>
__global__ __launch_bounds__(256) void k_gemm(const float* __restrict__ A,
                                              const float* __restrict__ Bm,
                                              const float* __restrict__ bias,
                                              float* __restrict__ C, int ldc) {
    __shared__ float sA[64 * 68];
    __shared__ float sB[64 * 68];
    const int tid = threadIdx.x;
    const int bx = blockIdx.x, by = blockIdx.y;
    const float* Ab = A + (size_t)by * 64 * K;
    const float* Bb = Bm + (size_t)bx * 64 * K;
    const int k4 = K >> 2;
    for (int fi = tid; fi < 64 * k4; fi += 256) {
        int r = fi / k4, c = fi % k4;
        float4 av = reinterpret_cast<const float4*>(Ab + (size_t)r * K)[c];
        *reinterpret_cast<float4*>(&sA[r * 68 + c * 4]) = av;
        float4 bv = reinterpret_cast<const float4*>(Bb + (size_t)r * K)[c];
        *reinterpret_cast<float4*>(&sB[r * 68 + c * 4]) = bv;
    }
    __syncthreads();
    const int tx = tid & 15, ty = tid >> 4;
    float acc[4][4];
#pragma unroll
    for (int i = 0; i < 4; i++)
#pragma unroll
        for (int j = 0; j < 4; j++) acc[i][j] = 0.0f;
    for (int k = 0; k < K; k += 4) {
        float4 av[4], bv[4];
#pragma unroll
        for (int i = 0; i < 4; i++) av[i] = *reinterpret_cast<const float4*>(&sA[(ty + 16 * i) * 68 + k]);
#pragma unroll
        for (int j = 0; j < 4; j++) bv[j] = *reinterpret_cast<const float4*>(&sB[(tx + 16 * j) * 68 + k]);
#pragma unroll
        for (int i = 0; i < 4; i++)
#pragma unroll
            for (int j = 0; j < 4; j++) {
                acc[i][j] += av[i].x * bv[j].x;
                acc[i][j] += av[i].y * bv[j].y;
                acc[i][j] += av[i].z * bv[j].z;
                acc[i][j] += av[i].w * bv[j].w;
            }
    }
#pragma unroll
    for (int i = 0; i < 4; i++) {
        size_t row = (size_t)by * 64 + ty + 16 * i;
#pragma unroll
        for (int j = 0; j < 4; j++) {
            int col = bx * 64 + tx + 16 * j;
            float v = acc[i][j];
            if (bias) v += bias[col];
            C[row * ldc + col] = v;
        }
    }
}

// ---------------- message + scatter (coalesced, 1 edge/block, inv_deg folded) ----------------
// msg[f] = sum_d out[src,d]*Wt[e][f*64+d]; thread t covers elements 16t..16t+15 (f=t>>2).
__global__ __launch_bounds__(256) void k_msg(const __hip_bfloat16* __restrict__ Wt,
                                             const float* __restrict__ out,
                                             const int* __restrict__ ei,
                                             const float* __restrict__ invd,
                                             int e0,
                                             float* __restrict__ agg) {
    const int ec = blockIdx.x;
    const int e = e0 + ec;
    const int t = threadIdx.x;
    const int src = ei[e], dst = ei[EE + e];
    const float iv = invd[dst];
    __shared__ float so[64];
    if (t < 64) so[t] = out[(size_t)src * 64 + t];
    __syncthreads();
    const uint4* wp = reinterpret_cast<const uint4*>(Wt + (size_t)ec * 4096) + t * 2;
    uint4 u0 = wp[0], u1 = wp[1];
    const float* o = so + (t & 3) * 16;
    float acc = 0.0f;
    acc += o[0] * bflo(u0.x) + o[1] * bfhi(u0.x);
    acc += o[2] * bflo(u0.y) + o[3] * bfhi(u0.y);
    acc += o[4] * bflo(u0.z) + o[5] * bfhi(u0.z);
    acc += o[6] * bflo(u0.w) + o[7] * bfhi(u0.w);
    acc += o[8] * bflo(u1.x) + o[9] * bfhi(u1.x);
    acc += o[10] * bflo(u1.y) + o[11] * bfhi(u1.y);
    acc += o[12] * bflo(u1.z) + o[13] * bfhi(u1.z);
    acc += o[14] * bflo(u1.w) + o[15] * bfhi(u1.w);
    acc += __shfl_xor(acc, 1, 64);
    acc += __shfl_xor(acc, 2, 64);
    if ((t & 3) == 0) atomicAdd(&agg[(size_t)dst * 64 + (t >> 2)], acc * iv);
}

// ---------------- m = relu(agg + rootC + conv_b) ----------------
__global__ __launch_bounds__(256) void k_m(const float* __restrict__ agg,
                                           const float* __restrict__ rootC,
                                           const float* __restrict__ cb,
                                           float* __restrict__ m) {
    int idx = blockIdx.x * 256 + threadIdx.x;
    int d = idx & 63;
    m[idx] = fmaxf(agg[idx] + rootC[idx] + cb[d], 0.0f);
}

// ---------------- GRU elementwise ----------------
__global__ __launch_bounds__(256) void k_gru(const float* __restrict__ gx,
                                             const float* __restrict__ gh,
                                             float* __restrict__ out) {
    int idx = blockIdx.x * 256 + threadIdx.x;
    int n = idx >> 6, d = idx & 63;
    const float* gxr = gx + (size_t)n * 192;
    const float* ghr = gh + (size_t)n * 192;
    float r = sigmoidf_(gxr[d] + ghr[d]);
    float z = sigmoidf_(gxr[64 + d] + ghr[64 + d]);
    float nn_ = tanhf(gxr[128 + d] + r * ghr[128 + d]);
    float hp = out[idx];
    out[idx] = (1.0f - z) * nn_ + z * hp;
}

// ---------------- batch counting + scan ----------------
__global__ __launch_bounds__(256) void k_cntbatch(const int* __restrict__ batch, int* __restrict__ cnt) {
    int n = blockIdx.x * 256 + threadIdx.x;
    if (n < NN) atomicAdd(&cnt[batch[n]], 1);
}
__global__ __launch_bounds__(256) void k_scan(const int* __restrict__ cnt, int* __restrict__ offs) {
    __shared__ int s[256];
    int t = threadIdx.x;
    s[t] = cnt[t];
    __syncthreads();
    for (int off = 1; off < 256; off <<= 1) {
        int v = (t >= off) ? s[t - off] : 0;
        __syncthreads();
        s[t] += v;
        __syncthreads();
    }
    offs[t + 1] = s[t];
    if (t == 0) offs[0] = 0;
}

// ---------------- Set2Set LSTM step ----------------
__global__ __launch_bounds__(256) void k_s2s(const float* __restrict__ qstar,
                                             float* __restrict__ qh, float* __restrict__ qc,
                                             const float* __restrict__ wih, const float* __restrict__ whh,
                                             const float* __restrict__ bih, const float* __restrict__ bhh) {
    int b = blockIdx.x, j = threadIdx.x;
    float g = bih[j] + bhh[j];
    const float* qs = qstar + (size_t)b * 128;
    const float* qhr = qh + (size_t)b * 64;
    for (int k = 0; k < 128; k++) g += qs[k] * wih[j * 128 + k];
    for (int k = 0; k < 64; k++) g += qhr[k] * whh[j * 64 + k];
    __shared__ float sg[256];
    sg[j] = g;
    __syncthreads();
    if (j < 64) {
        float gi = sg[j], gf = sg[64 + j], gg = sg[128 + j], go = sg[192 + j];
        float c = sigmoidf_(gf) * qc[b * 64 + j] + sigmoidf_(gi) * tanhf(gg);
        float h = sigmoidf_(go) * tanhf(c);
        qc[b * 64 + j] = c;
        qh[b * 64 + j] = h;
    }
}

// ---------------- e[n] = dot(out[n,:], qh[batch[n],:]) ----------------
__global__ __launch_bounds__(256) void k_e(const float* __restrict__ out,
                                           const float* __restrict__ qh,
                                           const int* __restrict__ batch,
                                           float* __restrict__ earr) {
    int n = blockIdx.x * 4 + (threadIdx.x >> 6);
    int lane = threadIdx.x & 63;
    float p = out[(size_t)n * 64 + lane] * qh[(size_t)batch[n] * 64 + lane];
#pragma unroll
    for (int o = 32; o > 0; o >>= 1) p += __shfl_xor(p, o, 64);
    if (lane == 0) earr[n] = p;
}

// ---------------- per-graph softmax + weighted sum -> q_star ----------------
__global__ __launch_bounds__(64) void k_seg(const int* __restrict__ offs,
                                            const float* __restrict__ earr,
                                            const float* __restrict__ out,
                                            const float* __restrict__ qh,
                                            float* __restrict__ qstar) {
    int b = blockIdx.x, lane = threadIdx.x;
    int s0 = offs[b], s1 = offs[b + 1];
    float mx = -INFINITY;
    for (int i = s0 + lane; i < s1; i += 64) mx = fmaxf(mx, earr[i]);
#pragma unroll
    for (int o = 32; o > 0; o >>= 1) mx = fmaxf(mx, __shfl_xor(mx, o, 64));
    if (!isfinite(mx)) mx = 0.0f;
    float sm = 0.0f;
    for (int i = s0 + lane; i < s1; i += 64) sm += expf(earr[i] - mx);
#pragma unroll
    for (int o = 32; o > 0; o >>= 1) sm += __shfl_xor(sm, o, 64);
    float r = 0.0f;
    for (int i = s0; i < s1; i++) r += expf(earr[i] - mx) * out[(size_t)i * 64 + lane];
    r /= fmaxf(sm, 1e-12f);
    qstar[(size_t)b * 128 + 64 + lane] = r;
    qstar[(size_t)b * 128 + lane] = qh[(size_t)b * 64 + lane];
}

// ---------------- head ----------------
__global__ __launch_bounds__(64) void k_final(const float* __restrict__ qstar,
                                              const float* __restrict__ w1, const float* __restrict__ b1,
                                              const float* __restrict__ w2, const float* __restrict__ b2,
                                              float* __restrict__ y) {
    int b = blockIdx.x, j = threadIdx.x;
    float h = b1[j];
    const float* qs = qstar + (size_t)b * 128;
    for (int k = 0; k < 128; k++) h += qs[k] * w1[j * 128 + k];
    h = fmaxf(h, 0.0f);
    float p = h * w2[j];
#pragma unroll
    for (int o = 32; o > 0; o >>= 1) p += __shfl_xor(p, o, 64);
    if (j == 0) y[b] = p + b2[0];
}

extern "C" void kernel_launch(void* const* d_in, const int* in_sizes, int n_in,
                              void* d_out, int out_size, void* d_ws, size_t ws_size,
                              hipStream_t stream) {
    const float* x = (const float*)d_in[0];
    const float* edge_attr = (const float*)d_in[1];
    const float* lin0_w = (const float*)d_in[2];
    const float* lin0_b = (const float*)d_in[3];
    const float* nn1_w = (const float*)d_in[4];
    const float* nn1_b = (const float*)d_in[5];
    const float* nn2_w = (const float*)d_in[6];
    const float* nn2_b = (const float*)d_in[7];
    const float* root_w = (const float*)d_in[8];
    const float* conv_b = (const float*)d_in[9];
    const float* gru_w_ih = (const float*)d_in[10];
    const float* gru_w_hh = (const float*)d_in[11];
    const float* gru_b_ih = (const float*)d_in[12];
    const float* gru_b_hh = (const float*)d_in[13];
    const float* s2s_w_ih = (const float*)d_in[14];
    const float* s2s_w_hh = (const float*)d_in[15];
    const float* s2s_b_ih = (const float*)d_in[16];
    const float* s2s_b_hh = (const float*)d_in[17];
    const float* lin1_w = (const float*)d_in[18];
    const float* lin1_b = (const float*)d_in[19];
    const float* lin2_w = (const float*)d_in[20];
    const float* lin2_b = (const float*)d_in[21];
    const int* ei = (const int*)d_in[22];
    const int* batch = (const int*)d_in[23];
    float* outp = (float*)d_out;

    char* w = (char*)d_ws;
    auto carve = [&](size_t bytes) { char* p = w; w += (bytes + 255) & ~(size_t)255; return p; };
    __hip_bfloat16* nn2P = (__hip_bfloat16*)carve((size_t)4096 * 128 * 2);
    float* bP = (float*)carve(4096 * 4);
    float* outN = (float*)carve((size_t)NN * 64 * 4);
    __hip_bfloat16* h1 = (__hip_bfloat16*)carve((size_t)EE * 128 * 2);
    int* deg = (int*)carve(NN * 4);
    float* invd = (float*)carve(NN * 4);
    float* agg = (float*)carve((size_t)NN * 64 * 4);
    float* rootC = (float*)carve((size_t)NN * 64 * 4);
    float* mbuf = (float*)carve((size_t)NN * 64 * 4);
    float* gx = (float*)carve((size_t)NN * 192 * 4);
    float* gh = (float*)carve((size_t)NN * 192 * 4);
    float* earr = (float*)carve(NN * 4);
    int* cnt = (int*)carve(256 * 4);
    int* offs = (int*)carve(257 * 4);
    float* qh = (float*)carve((size_t)BB * 64 * 4);
    float* qc = (float*)carve((size_t)BB * 64 * 4);
    float* qstar = (float*)carve((size_t)BB * 128 * 4);
    size_t used = (size_t)(w - (char*)d_ws);
    size_t remain = ws_size > used ? ws_size - used : 0;
    size_t cap = (remain / ((size_t)4096 * 2)) & ~(size_t)127;   // edges that fit, multiple of 128
    int chunkE = (int)(cap > (size_t)EE ? (size_t)EE : cap);
    if (chunkE < 128) chunkE = 128;
    bool persist = (chunkE >= EE);
    if (persist) chunkE = EE;
    __hip_bfloat16* Wt = (__hip_bfloat16*)w;

    hipMemsetAsync(deg, 0, NN * 4, stream);
    hipMemsetAsync(cnt, 0, 256 * 4, stream);
    hipMemsetAsync(qh, 0, BB * 64 * 4, stream);
    hipMemsetAsync(qc, 0, BB * 64 * 4, stream);
    hipMemsetAsync(qstar, 0, BB * 128 * 4, stream);

    k_permute<<<2048, 256, 0, stream>>>(nn2_w, nn2_b, nn2P, bP);
    k_lin0<<<NN * 64 / 256, 256, 0, stream>>>(x, lin0_w, lin0_b, outN);
    k_h1<<<EE * 128 / 256, 256, 0, stream>>>(edge_attr, nn1_w, nn1_b, h1);
    k_count<<<EE / 256, 256, 0, stream>>>(ei, deg);
    k_inv<<<NN / 256, 256, 0, stream>>>(deg, invd);
    k_cntbatch<<<NN / 256, 256, 0, stream>>>(batch, cnt);
    k_scan<<<1, 256, 0, stream>>>(cnt, offs);

    if (persist)
        k_we<<<dim3(32, EE / 128), 256, 0, stream>>>(h1, nn2P, bP, Wt);

    for (int it = 0; it < 3; it++) {
        hipMemsetAsync(agg, 0, (size_t)NN * 64 * 4, stream);
        for (int e0 = 0; e0 < EE; e0 += chunkE) {
            int ce = (EE - e0) < chunkE ? (EE - e0) : chunkE;
            if (!persist)
                k_we<<<dim3(32, ce / 128), 256, 0, stream>>>(h1 + (size_t)e0 * 128, nn2P, bP, Wt);
            k_msg<<<ce, 256, 0, stream>>>(Wt, outN, ei, invd, e0, agg);
        }
        k_gemm<64><<<dim3(1, NN / 64), 256, 0, stream>>>(outN, root_w, nullptr, rootC, 64);
        k_m<<<NN * 64 / 256, 256, 0, stream>>>(agg, rootC, conv_b, mbuf);
        k_gemm<64><<<dim3(3, NN / 64), 256, 0, stream>>>(mbuf, gru_w_ih, gru_b_ih, gx, 192);
        k_gemm<64><<<dim3(3, NN / 64), 256, 0, stream>>>(outN, gru_w_hh, gru_b_hh, gh, 192);
        k_gru<<<NN * 64 / 256, 256, 0, stream>>>(gx, gh, outN);
    }

    for (int st = 0; st < 3; st++) {
        k_s2s<<<BB, 256, 0, stream>>>(qstar, qh, qc, s2s_w_ih, s2s_w_hh, s2s_b_ih, s2s_b_hh);
        k_e<<<NN / 4, 256, 0, stream>>>(outN, qh, batch, earr);
        k_seg<<<BB, 64, 0, stream>>>(offs, earr, outN, qh, qstar);
    }
    k_final<<<BB, 64, 0, stream>>>(qstar, lin1_w, lin1_b, lin2_w, lin2_b, outp);
}